// Round 3
// baseline (1336.886 us; speedup 1.0000x reference)
//
#include <hip/hip_runtime.h>
#include <hip/hip_bf16.h>

typedef __attribute__((ext_vector_type(8))) short short8;
typedef __attribute__((ext_vector_type(4))) float f32x4;
typedef __attribute__((ext_vector_type(4))) int   i32x4;
typedef __hip_bfloat16 bf16_t;

#define HH 224
#define WW 224
#define HWSZ (224*224)
#define NIMG 16

// x (N,Cin,224,224) f32  ->  xc [N][224][Cin/32][224][32] bf16
template<int CIN>
__global__ __launch_bounds__(256)
void prep_x(const float* __restrict__ x, bf16_t* __restrict__ xc) {
  constexpr int NCC = CIN/32;
  __shared__ float tile[32][225];
  int b = blockIdx.x;
  int cc = b % NCC; int h = (b/NCC) % HH; int n = b / (NCC*HH);
  const float* src = x + ((long)(n*CIN + cc*32))*HWSZ + (long)h*WW;
  for (int i = threadIdx.x; i < 32*WW; i += 256) {
    int ci = i / WW, w = i - ci*WW;
    tile[ci][w] = src[(long)ci*HWSZ + w];
  }
  __syncthreads();
  bf16_t* dst = xc + ((long)(n*HH + h)*NCC + cc)*(WW*32);
  for (int i = threadIdx.x; i < WW*32; i += 256) {
    int w = i >> 5, ci = i & 31;
    dst[i] = __float2bfloat16(tile[ci][w]);
  }
}

// w (Cout,Cin,3,3) f32 -> wb [t][co][ci] bf16,  t = kh*3+kw
__global__ __launch_bounds__(256)
void prep_w(const float* __restrict__ w, bf16_t* __restrict__ wb, int Cout, int Cin) {
  int idx = blockIdx.x*256 + threadIdx.x;
  if (idx >= 9*Cout*Cin) return;
  int ci = idx % Cin; int r = idx / Cin; int co = r % Cout; int t = r / Cout;
  wb[idx] = __float2bfloat16(w[((long)co*Cin + ci)*9 + t]);
}

// Implicit-GEMM 3x3 conv, stride1 pad1.
// in : [N][224][CIN/32][224][32] bf16
// wb : [9][COUT][CIN] bf16
// out: FINAL ? [N][COUT][224][224] f32 : [N][224][COUT/32][224][32] bf16
//
// Block tile: 2 rows x 112 cols x COUT (grid.y=1 -> input staged ONCE for all couts;
// round-2 FETCH showed 2x over-read from the old co-split).
// T threads = T/64 waves; wave = (row rw in 2) x (co-quarter coq in COUT/16). NQ=1:
// acc is only 7 f32x4/thread -> fits 4 waves/SIMD at <=128 VGPR.
// LDS: double-buffered 4 rows x 114 cols x 32ci = 2 x 29184 B = 58368 B (<64KB static).
// Pipeline per ci-chunk (T14 async-split): issue next-chunk global loads BEFORE the
// 63-MFMA phase, ds_write AFTER, one barrier per chunk.
template<int CIN, int COUT, int T, bool FINAL>
__global__ __launch_bounds__(T, 4)
void conv3x3(const bf16_t* __restrict__ in, const bf16_t* __restrict__ wb,
             void* __restrict__ outp)
{
  constexpr int NCC  = CIN/32;
  constexpr int NCOQ = COUT/16;        // co-quarters; waves = 2*NCOQ = T/64
  constexpr int ROWB = 114*64;         // 7296 B per staged row
  constexpr int BUFB = 4*ROWB;         // 29184 B per buffer
  constexpr int SLOTS = BUFB/16;       // 1824 16B slots
  constexpr int NLD  = (SLOTS + T - 1)/T;
  __shared__ char lds_x[2*BUFB];       // 58368 B

  const int tid  = threadIdx.x;
  const int lane = tid & 63;
  const int l15  = lane & 15;
  const int lk   = lane >> 4;
  const int wv   = tid >> 6;
  const int rw   = wv / NCOQ;          // tile row 0/1
  const int coq  = wv % NCOQ;          // 16-cout group

  // XCD-aware bijective swizzle: 3584 blocks, 448 contiguous work items per XCD.
  // Work order (n, h-tile, col-half) -> halo rows shared within an XCD (L2 hits).
  constexpr int NWG = NIMG*112*2;      // 3584, %8==0
  int bid = blockIdx.x;
  int wk  = (bid & 7)*(NWG/8) + (bid >> 3);
  const int n   = wk / 224;
  int rem = wk - n*224;
  const int h0  = (rem >> 1)*2;
  const int c0  = (rem & 1)*112;       // output col base

  f32x4 acc[7];
  #pragma unroll
  for (int m=0;m<7;++m) acc[m] = (f32x4){0.f,0.f,0.f,0.f};

  const bf16_t* inb   = in + (long)n*HH*NCC*WW*32;
  const bf16_t* wlane = wb + (long)(coq*16 + l15)*CIN + lk*8;

  i32x4 sreg[NLD];

  auto stage_load = [&](int c) {
    #pragma unroll
    for (int u=0; u<NLD; ++u) {
      int idx = tid + u*T;
      sreg[u] = (i32x4){0,0,0,0};
      if (idx < SLOTS) {
        int i = idx/456; int r456 = idx - i*456;   // 456 slots per row
        int j = r456 >> 2; int q = r456 & 3;       // lds col, 16B quarter
        int hh = h0 - 1 + i;
        int icol = c0 + j - 1;
        if ((unsigned)hh < (unsigned)HH && (unsigned)icol < (unsigned)WW) {
          const char* p = (const char*)(inb + (((long)hh*NCC + c)*WW + icol)*32) + q*16;
          sreg[u] = *(const i32x4*)p;
        }
      }
    }
  };
  auto stage_write = [&](char* buf) {
    #pragma unroll
    for (int u=0; u<NLD; ++u) {
      int idx = tid + u*T;
      if (idx < SLOTS) {
        int a = idx*16;
        a ^= ((a>>7)&3)<<4;            // bank swizzle (verified: 0 conflicts in r2)
        *(i32x4*)(buf + a) = sreg[u];
      }
    }
  };

  stage_load(0);
  stage_write(lds_x);
  __syncthreads();
  int cur = 0;

  for (int c = 0; c < NCC; ++c) {
    if (c+1 < NCC) stage_load(c+1);            // issue early: latency hides under MFMA
    const bf16_t* wc = wlane + c*32;
    const char* buf = lds_x + cur*BUFB;
    short8 bf = *(const short8*)wc;            // tap 0 B-frag (L2-resident)
    #pragma unroll
    for (int t=0; t<9; ++t) {
      short8 bfn;
      if (t<8) bfn = *(const short8*)(wc + (long)(t+1)*COUT*CIN);
      int dh = t/3, dw = t - dh*3;
      int arow = (rw+dh)*ROWB;
      #pragma unroll
      for (int m=0;m<7;++m) {
        int a = arow + (m*16 + l15 + dw)*64 + lk*16;
        a ^= ((a>>7)&3)<<4;
        short8 af = *(const short8*)(buf + a);
        acc[m] = __builtin_amdgcn_mfma_f32_16x16x32_bf16(af, bf, acc[m], 0,0,0);
      }
      if (t<8) bf = bfn;
    }
    if (c+1 < NCC) stage_write(lds_x + (cur^1)*BUFB);  // write late (loads landed)
    __syncthreads();
    cur ^= 1;
  }

  // ---- epilogue ----  D: col(l15)=co, row(lk*4+jj)=pixel (validated in r2)
  const int orow = h0 + rw;
  const int co   = coq*16 + l15;
  if (!FINAL) {
    bf16_t* out = (bf16_t*)outp;
    constexpr int NCO = COUT/32;
    long ob = (((long)n*HH + orow)*NCO + (co>>5))*((long)WW*32) + (co&31);
    #pragma unroll
    for (int m=0;m<7;++m) {
      int col = c0 + m*16 + lk*4;
      #pragma unroll
      for (int jj=0;jj<4;++jj)
        out[ob + (long)(col+jj)*32] = __float2bfloat16(acc[m][jj]);
    }
  } else {
    float* out = (float*)outp;
    long ob = (((long)n*COUT + co)*HH + orow)*(long)WW;
    #pragma unroll
    for (int m=0;m<7;++m) {
      int col = c0 + m*16 + lk*4;
      *(f32x4*)(out + ob + col) = acc[m];
    }
  }
}

extern "C" void kernel_launch(void* const* d_in, const int* in_sizes, int n_in,
                              void* d_out, int out_size, void* d_ws, size_t ws_size,
                              hipStream_t stream) {
  (void)in_sizes; (void)n_in; (void)out_size; (void)ws_size;
  const float* x  = (const float*)d_in[0];
  const float* w1 = (const float*)d_in[1];
  const float* w2 = (const float*)d_in[2];
  const float* w3 = (const float*)d_in[3];

  // Buffer plan (peak d_ws use = 196.6 MiB):
  //   SB = one full 128-ch bf16 activation tensor = 205,520,896 B
  //   d_out (same byte size!) doubles as a1 (conv1 output bf16) until conv3 overwrites
  const size_t SB = (size_t)NIMG*HH*WW*128*2;
  char* ws = (char*)d_ws;
  bf16_t* bufA = (bf16_t*)ws;            // xc (conv1 in), later a2 (conv2 out)
  bf16_t* a1   = (bf16_t*)d_out;         // conv1 out lives in d_out until conv3
  bf16_t* wb1  = (bf16_t*)(ws + SB);
  bf16_t* wb2  = wb1 + 9*128*64;
  bf16_t* wb3  = wb2 + 9*128*128;

  prep_x<64><<<NIMG*HH*2, 256, 0, stream>>>(x, bufA);
  prep_w<<<(9*128*64 + 255)/256, 256, 0, stream>>>(w1, wb1, 128, 64);
  prep_w<<<(9*128*128 + 255)/256, 256, 0, stream>>>(w2, wb2, 128, 128);
  prep_w<<<(9*64*128 + 255)/256, 256, 0, stream>>>(w3, wb3, 64, 128);

  conv3x3<64,128,1024,false><<<NIMG*112*2, 1024, 0, stream>>>(bufA, wb1, a1);
  conv3x3<128,128,1024,false><<<NIMG*112*2, 1024, 0, stream>>>(a1, wb2, bufA);
  conv3x3<128,64,512,true ><<<NIMG*112*2, 512, 0, stream>>>(bufA, wb3, (float*)d_out);
}